// Round 1
// baseline (241.988 us; speedup 1.0000x reference)
//
#include <hip/hip_runtime.h>

typedef __bf16 bf16x8 __attribute__((ext_vector_type(8)));
typedef float f32x4 __attribute__((ext_vector_type(4)));

__device__ __forceinline__ unsigned short f2bf(float f) {
  return __builtin_bit_cast(unsigned short, (__bf16)f);
}
__device__ __forceinline__ float bfu2f(unsigned short b) {
  unsigned int u = ((unsigned int)b) << 16;
  return __builtin_bit_cast(float, u);
}
__device__ __forceinline__ float silu_f(float x) {
  return x / (1.0f + __expf(-x));
}

// Stage a tile of (64*NI*4/CPR... ) rows x (CPR*8) cols bf16 into LDS, 16B chunks,
// row-major contiguous (global_load_lds: wave-uniform LDS base + lane*16).
template<int CPR, int NI>
__device__ __forceinline__ void stage16(const __bf16* __restrict__ g, int ld,
                                        __bf16* lds, int wave, int lane) {
#pragma unroll
  for (int t = 0; t < NI; ++t) {
    int cb = (wave * NI + t) * 64;
    int c = cb + lane;
    int row = c / CPR;
    int col = (c % CPR) * 8;
    __builtin_amdgcn_global_load_lds(
        (const __attribute__((address_space(1))) unsigned int*)(g + row * ld + col),
        (__attribute__((address_space(3))) unsigned int*)(lds + cb * 8),
        16, 0, 0);
  }
}

// ---------------- prep kernels ----------------

// uvqk (512 x 2048 fp32) -> uvqkT (2048 x 512 bf16)  [B^T layout for GEMM]
__global__ void k_tr_uvqk(const float* __restrict__ uvqk, __bf16* __restrict__ uvqkT) {
  __shared__ float tile[32][33];
  int n0 = blockIdx.x * 32, k0 = blockIdx.y * 32;
  int tx = threadIdx.x, ty = threadIdx.y;
  for (int i = ty; i < 32; i += 8)
    tile[i][tx] = uvqk[(k0 + i) * 2048 + n0 + tx];
  __syncthreads();
  for (int i = ty; i < 32; i += 8)
    uvqkT[(n0 + i) * 512 + k0 + tx] = (__bf16)tile[tx][i];
}

// o_weight (512 x 512 fp32, already B^T layout) -> bf16
__global__ void k_cv_ow(const float* __restrict__ ow, __bf16* __restrict__ owb) {
  int i = blockIdx.x * 256 + threadIdx.x;
  float4 v = ((const float4*)ow)[i];
  ushort4 o4;
  o4.x = f2bf(v.x); o4.y = f2bf(v.y); o4.z = f2bf(v.z); o4.w = f2bf(v.w);
  ((ushort4*)owb)[i] = o4;
}

// layer_norm(x) -> bf16, one block (128 thr) per row of 512
__global__ void k_ln_x(const float* __restrict__ x, __bf16* __restrict__ nx) {
  int r = blockIdx.x, t = threadIdx.x;
  float4 v = ((const float4*)(x + (size_t)r * 512))[t];
  float s = v.x + v.y + v.z + v.w;
  float ss = v.x * v.x + v.y * v.y + v.z * v.z + v.w * v.w;
#pragma unroll
  for (int o = 32; o > 0; o >>= 1) { s += __shfl_down(s, o); ss += __shfl_down(ss, o); }
  __shared__ float red[4];
  if ((t & 63) == 0) { red[(t >> 6) * 2] = s; red[(t >> 6) * 2 + 1] = ss; }
  __syncthreads();
  s = red[0] + red[2]; ss = red[1] + red[3];
  float mu = s * (1.0f / 512.0f);
  float var = ss * (1.0f / 512.0f) - mu * mu;
  float rs = rsqrtf(var + 1e-6f);
  ushort4 o4;
  o4.x = f2bf((v.x - mu) * rs); o4.y = f2bf((v.y - mu) * rs);
  o4.z = f2bf((v.z - mu) * rs); o4.w = f2bf((v.w - mu) * rs);
  ((ushort4*)(nx + (size_t)r * 512))[t] = o4;
}

// ---------------- projection GEMM: mm = silu(nx @ uvqk), split epilogue ----------------
// M=8192, N=2048, K=512. 128x128 tile, 4 waves 2x2, 16x16x32 MFMA.
__global__ __launch_bounds__(256, 2) void k_proj(
    const __bf16* __restrict__ A, const __bf16* __restrict__ Bt,
    __bf16* __restrict__ u, __bf16* __restrict__ qn,
    __bf16* __restrict__ kn, __bf16* __restrict__ vt) {
  __shared__ __bf16 As[128 * 32], Bs[128 * 32];
  int tid = threadIdx.x, wave = tid >> 6, lane = tid & 63;
  int lr = lane & 15, lq = lane >> 4;
  int bn = blockIdx.x, bm = blockIdx.y;
  const __bf16* Ag = A + (size_t)bm * 128 * 512;
  const __bf16* Bg = Bt + (size_t)bn * 128 * 512;
  int wm = (wave >> 1) * 64, wn = (wave & 1) * 64;
  f32x4 acc[4][4] = {};
  for (int k0 = 0; k0 < 512; k0 += 32) {
    stage16<4, 2>(Ag + k0, 512, As, wave, lane);
    stage16<4, 2>(Bg + k0, 512, Bs, wave, lane);
    __syncthreads();
    bf16x8 a[4], bb[4];
#pragma unroll
    for (int i = 0; i < 4; ++i)
      a[i] = *(const bf16x8*)(As + (wm + i * 16 + lr) * 32 + lq * 8);
#pragma unroll
    for (int j = 0; j < 4; ++j)
      bb[j] = *(const bf16x8*)(Bs + (wn + j * 16 + lr) * 32 + lq * 8);
#pragma unroll
    for (int i = 0; i < 4; ++i)
#pragma unroll
      for (int j = 0; j < 4; ++j)
        acc[i][j] = __builtin_amdgcn_mfma_f32_16x16x32_bf16(a[i], bb[j], acc[i][j], 0, 0, 0);
    __syncthreads();
  }
  // epilogue: seg 0=u, 1=v(->vt transposed), 2=q, 3=k; silu applied here
  int seg = bn >> 2;
  int cb = (bn & 3) * 128 + wn;
  int rb0 = bm * 128 + wm + lq * 4;
  if (seg == 1) {
#pragma unroll
    for (int i = 0; i < 4; ++i) {
      int rb = rb0 + i * 16;
      int b = rb >> 11, n = rb & 2047;
#pragma unroll
      for (int j = 0; j < 4; ++j) {
        int c = cb + j * 16 + lr;  // h*64+dl
        ushort4 w;
        w.x = f2bf(silu_f(acc[i][j][0]));
        w.y = f2bf(silu_f(acc[i][j][1]));
        w.z = f2bf(silu_f(acc[i][j][2]));
        w.w = f2bf(silu_f(acc[i][j][3]));
        *(ushort4*)(vt + ((size_t)(b * 512 + c)) * 2048 + n) = w;
      }
    }
  } else {
    __bf16* dst = (seg == 0) ? u : ((seg == 2) ? qn : kn);
#pragma unroll
    for (int i = 0; i < 4; ++i) {
      int rb = rb0 + i * 16;
#pragma unroll
      for (int j = 0; j < 4; ++j) {
        int c = cb + j * 16 + lr;
#pragma unroll
        for (int rg = 0; rg < 4; ++rg)
          dst[(size_t)(rb + rg) * 512 + c] = (__bf16)silu_f(acc[i][j][rg]);
      }
    }
  }
}

// ---------------- fused causal silu-attention ----------------
// Per (b,h): Q-tile 128 rows. Loop causal m-tiles of 128:
//   S^T = K·Q^T (MFMA), P = mask·silu(S)/2048 -> LDS (padded panels), out^T += V^T·P^T.
__global__ __launch_bounds__(256, 2) void k_attn(
    const __bf16* __restrict__ qn, const __bf16* __restrict__ kn,
    const __bf16* __restrict__ vt, __bf16* __restrict__ attn) {
  __shared__ __bf16 lds[34816];
  __bf16* Ps = lds;           // 4 panels x 128 x 36 (pad 4) = 18432; Q staged here first
  __bf16* Ks = lds + 18432;   // 2 panels x 128 x 32
  __bf16* Vs = lds + 26624;   // 4 panels x 64 x 32
  int bh = blockIdx.x;
  int yy = blockIdx.y;
  int qt = (yy < 8) ? yy : 23 - yy;  // heavy/light pairing across CUs
  int b = bh >> 3, h = bh & 7;
  int tid = threadIdx.x, wave = tid >> 6, lane = tid & 63;
  int lr = lane & 15, lq = lane >> 4;
  int n0 = qt * 128;
  const __bf16* Qg = qn + (size_t)(b * 2048 + n0) * 512 + h * 64;
  const __bf16* Kg = kn + (size_t)(b * 2048) * 512 + h * 64;
  const __bf16* Vg = vt + (size_t)(b * 512 + h * 64) * 2048;

  stage16<4, 2>(Qg, 512, Ps, wave, lane);
  stage16<4, 2>(Qg + 32, 512, Ps + 4096, wave, lane);
  stage16<4, 2>(Kg, 512, Ks, wave, lane);
  stage16<4, 2>(Kg + 32, 512, Ks + 4096, wave, lane);
#pragma unroll
  for (int p = 0; p < 4; ++p)
    stage16<4, 1>(Vg + p * 32, 2048, Vs + p * 2048, wave, lane);
  __syncthreads();

  int wmS = (wave >> 1) * 64, wnS = (wave & 1) * 64;  // S^T: m rows, n cols
  bf16x8 qf[2][4];  // Q B-frags cached in registers (reused every m-tile)
#pragma unroll
  for (int kk = 0; kk < 2; ++kk)
#pragma unroll
    for (int j = 0; j < 4; ++j)
      qf[kk][j] = *(const bf16x8*)(Ps + kk * 4096 + (wnS + j * 16 + lr) * 32 + lq * 8);
  __syncthreads();  // Q region now reusable as Ps

  int wdl = (wave >> 1) * 32, wn2 = (wave & 1) * 64;  // out^T: dl rows, n cols
  f32x4 po[2][4] = {};

  for (int mt = 0; mt <= qt; ++mt) {
    if (mt > 0) {
      int m0 = mt * 128;
      stage16<4, 2>(Kg + (size_t)m0 * 512, 512, Ks, wave, lane);
      stage16<4, 2>(Kg + (size_t)m0 * 512 + 32, 512, Ks + 4096, wave, lane);
#pragma unroll
      for (int p = 0; p < 4; ++p)
        stage16<4, 1>(Vg + m0 + p * 32, 2048, Vs + p * 2048, wave, lane);
      __syncthreads();
    }
    // S^T = K·Q^T
    f32x4 s[4][4] = {};
#pragma unroll
    for (int kk = 0; kk < 2; ++kk) {
      bf16x8 ak[4];
#pragma unroll
      for (int i = 0; i < 4; ++i)
        ak[i] = *(const bf16x8*)(Ks + kk * 4096 + (wmS + i * 16 + lr) * 32 + lq * 8);
#pragma unroll
      for (int i = 0; i < 4; ++i)
#pragma unroll
        for (int j = 0; j < 4; ++j)
          s[i][j] = __builtin_amdgcn_mfma_f32_16x16x32_bf16(ak[i], qf[kk][j], s[i][j], 0, 0, 0);
    }
    // P = mask * silu(S)/2048, packed ds_write_b64 into padded panels
    bool diag = (mt == qt);
#pragma unroll
    for (int i = 0; i < 4; ++i) {
      int m_l = wmS + i * 16 + lq * 4;
      int panel = (wmS + i * 16) >> 5;
      int moff = m_l & 31;
#pragma unroll
      for (int j = 0; j < 4; ++j) {
        int n_l = wnS + j * 16 + lr;
        ushort4 w;
        float p0 = silu_f(s[i][j][0]) * (1.0f / 2048.0f);
        float p1 = silu_f(s[i][j][1]) * (1.0f / 2048.0f);
        float p2 = silu_f(s[i][j][2]) * (1.0f / 2048.0f);
        float p3 = silu_f(s[i][j][3]) * (1.0f / 2048.0f);
        if (diag) {
          if (m_l + 0 > n_l) p0 = 0.0f;
          if (m_l + 1 > n_l) p1 = 0.0f;
          if (m_l + 2 > n_l) p2 = 0.0f;
          if (m_l + 3 > n_l) p3 = 0.0f;
        }
        w.x = f2bf(p0); w.y = f2bf(p1); w.z = f2bf(p2); w.w = f2bf(p3);
        *(ushort4*)(Ps + panel * 4608 + n_l * 36 + moff) = w;
      }
    }
    __syncthreads();
    // out^T += V^T · P^T
#pragma unroll
    for (int ks = 0; ks < 4; ++ks) {
      bf16x8 av[2];
#pragma unroll
      for (int i = 0; i < 2; ++i)
        av[i] = *(const bf16x8*)(Vs + ks * 2048 + (wdl + i * 16 + lr) * 32 + lq * 8);
#pragma unroll
      for (int j = 0; j < 4; ++j) {
        const uint2* pp = (const uint2*)(Ps + ks * 4608 + (wn2 + j * 16 + lr) * 36 + lq * 8);
        union { bf16x8 v; uint2 u2[2]; } bp;
        bp.u2[0] = pp[0];
        bp.u2[1] = pp[1];
#pragma unroll
        for (int i = 0; i < 2; ++i)
          po[i][j] = __builtin_amdgcn_mfma_f32_16x16x32_bf16(av[i], bp.v, po[i][j], 0, 0, 0);
      }
    }
    __syncthreads();
  }
  // epilogue: attn[b,n,h*64+dl], 4 consecutive dl packed per lane
#pragma unroll
  for (int i = 0; i < 2; ++i) {
    int dl = wdl + i * 16 + lq * 4;
#pragma unroll
    for (int j = 0; j < 4; ++j) {
      int n = n0 + wn2 + j * 16 + lr;
      ushort4 w;
      w.x = f2bf(po[i][j][0]); w.y = f2bf(po[i][j][1]);
      w.z = f2bf(po[i][j][2]); w.w = f2bf(po[i][j][3]);
      *(ushort4*)(attn + (size_t)(b * 2048 + n) * 512 + h * 64 + dl) = w;
    }
  }
}

// o_input = u * layer_norm(attn), one block (128 thr) per row
__global__ void k_oinput(const __bf16* __restrict__ attn, const __bf16* __restrict__ u,
                         __bf16* __restrict__ oin) {
  int r = blockIdx.x, t = threadIdx.x;
  ushort4 a4 = ((const ushort4*)(attn + (size_t)r * 512))[t];
  float a0 = bfu2f(a4.x), a1 = bfu2f(a4.y), a2 = bfu2f(a4.z), a3 = bfu2f(a4.w);
  float s = a0 + a1 + a2 + a3;
  float ss = a0 * a0 + a1 * a1 + a2 * a2 + a3 * a3;
#pragma unroll
  for (int o = 32; o > 0; o >>= 1) { s += __shfl_down(s, o); ss += __shfl_down(ss, o); }
  __shared__ float red[4];
  if ((t & 63) == 0) { red[(t >> 6) * 2] = s; red[(t >> 6) * 2 + 1] = ss; }
  __syncthreads();
  s = red[0] + red[2]; ss = red[1] + red[3];
  float mu = s * (1.0f / 512.0f);
  float var = ss * (1.0f / 512.0f) - mu * mu;
  float rs = rsqrtf(var + 1e-6f);
  ushort4 u4 = ((const ushort4*)(u + (size_t)r * 512))[t];
  ushort4 o4;
  o4.x = f2bf(bfu2f(u4.x) * (a0 - mu) * rs);
  o4.y = f2bf(bfu2f(u4.y) * (a1 - mu) * rs);
  o4.z = f2bf(bfu2f(u4.z) * (a2 - mu) * rs);
  o4.w = f2bf(bfu2f(u4.w) * (a3 - mu) * rs);
  ((ushort4*)(oin + (size_t)r * 512))[t] = o4;
}

// out = o_in @ ow^T + bias + x.  M=8192, N=512, K=512
__global__ __launch_bounds__(256, 2) void k_out(
    const __bf16* __restrict__ A, const __bf16* __restrict__ Bt,
    const float* __restrict__ bias, const float* __restrict__ x,
    float* __restrict__ out) {
  __shared__ __bf16 As[128 * 32], Bs[128 * 32];
  int tid = threadIdx.x, wave = tid >> 6, lane = tid & 63;
  int lr = lane & 15, lq = lane >> 4;
  int bn = blockIdx.x, bm = blockIdx.y;
  const __bf16* Ag = A + (size_t)bm * 128 * 512;
  const __bf16* Bg = Bt + (size_t)bn * 128 * 512;
  int wm = (wave >> 1) * 64, wn = (wave & 1) * 64;
  f32x4 acc[4][4] = {};
  for (int k0 = 0; k0 < 512; k0 += 32) {
    stage16<4, 2>(Ag + k0, 512, As, wave, lane);
    stage16<4, 2>(Bg + k0, 512, Bs, wave, lane);
    __syncthreads();
    bf16x8 a[4], bb[4];
#pragma unroll
    for (int i = 0; i < 4; ++i)
      a[i] = *(const bf16x8*)(As + (wm + i * 16 + lr) * 32 + lq * 8);
#pragma unroll
    for (int j = 0; j < 4; ++j)
      bb[j] = *(const bf16x8*)(Bs + (wn + j * 16 + lr) * 32 + lq * 8);
#pragma unroll
    for (int i = 0; i < 4; ++i)
#pragma unroll
      for (int j = 0; j < 4; ++j)
        acc[i][j] = __builtin_amdgcn_mfma_f32_16x16x32_bf16(a[i], bb[j], acc[i][j], 0, 0, 0);
    __syncthreads();
  }
  int cb = bn * 128 + wn;
  int rb0 = bm * 128 + wm + lq * 4;
#pragma unroll
  for (int j = 0; j < 4; ++j) {
    int c = cb + j * 16 + lr;
    float bv = bias[c];
#pragma unroll
    for (int i = 0; i < 4; ++i) {
      int rb = rb0 + i * 16;
#pragma unroll
      for (int rg = 0; rg < 4; ++rg) {
        size_t idx = (size_t)(rb + rg) * 512 + c;
        out[idx] = acc[i][j][rg] + bv + x[idx];
      }
    }
  }
}

extern "C" void kernel_launch(void* const* d_in, const int* in_sizes, int n_in,
                              void* d_out, int out_size, void* d_ws, size_t ws_size,
                              hipStream_t stream) {
  const float* x = (const float*)d_in[0];
  // d_in[1] = attention_mask (deterministic causal tril) -- applied analytically
  const float* uvqk = (const float*)d_in[2];
  const float* ow = (const float*)d_in[3];
  const float* ob = (const float*)d_in[4];
  float* out = (float*)d_out;

  char* w = (char*)d_ws;
  const size_t MB8 = 8u * 1024 * 1024;
  __bf16* nx    = (__bf16*)(w);             // 8 MB
  __bf16* u     = (__bf16*)(w + MB8);       // 8 MB
  __bf16* qn    = (__bf16*)(w + 2 * MB8);   // 8 MB
  __bf16* kn    = (__bf16*)(w + 3 * MB8);   // 8 MB
  __bf16* vt    = (__bf16*)(w + 4 * MB8);   // 8 MB (b,h,dl,n)
  __bf16* uvqkT = (__bf16*)(w + 5 * MB8);   // 2 MB
  __bf16* owb   = (__bf16*)(w + 5 * MB8 + 2097152);  // 0.5 MB
  __bf16* attn  = nx;  // nx dead after k_proj
  __bf16* o_in  = qn;  // qn dead after k_attn

  k_tr_uvqk<<<dim3(64, 16), dim3(32, 8), 0, stream>>>(uvqk, uvqkT);
  k_cv_ow<<<256, 256, 0, stream>>>(ow, owb);
  k_ln_x<<<8192, 128, 0, stream>>>(x, nx);
  k_proj<<<dim3(16, 64), 256, 0, stream>>>(nx, uvqkT, u, qn, kn, vt);
  k_attn<<<dim3(32, 16), 256, 0, stream>>>(qn, kn, vt, attn);
  k_oinput<<<8192, 128, 0, stream>>>(attn, u, o_in);
  k_out<<<dim3(4, 64), 256, 0, stream>>>(o_in, owb, ob, x, out);
}

// Round 3
// 223.214 us; speedup vs baseline: 1.0841x; 1.0841x over previous
//
#include <hip/hip_runtime.h>

typedef __bf16 bf16x8 __attribute__((ext_vector_type(8)));
typedef float f32x4 __attribute__((ext_vector_type(4)));
typedef float f32x16 __attribute__((ext_vector_type(16)));

__device__ __forceinline__ unsigned short f2bf(float f) {
  return __builtin_bit_cast(unsigned short, (__bf16)f);
}
__device__ __forceinline__ float bfu2f(unsigned short b) {
  unsigned int u = ((unsigned int)b) << 16;
  return __builtin_bit_cast(float, u);
}
// fast silu: x * rcp(1+exp(-x)).  v_exp + v_rcp, no div sequence.
__device__ __forceinline__ float silu_f(float x) {
  return x * __builtin_amdgcn_rcpf(1.0f + __expf(-x));
}
__device__ __forceinline__ unsigned pk2(float a, float b) {
  return (unsigned)f2bf(a) | ((unsigned)f2bf(b) << 16);
}

// Stage rows x (CPR*8) cols bf16 into LDS, 16B chunks via global_load_lds.
// SWZ: store logical k-block at slot (k/8)^(row&3) (XOR on the *source* column,
// since the LDS dest is HW-fixed wave-base+lane*16). Only valid for CPR=4.
template<int CPR, int NI, bool SWZ = false>
__device__ __forceinline__ void stage16(const __bf16* __restrict__ g, int ld,
                                        __bf16* lds, int wave, int lane) {
#pragma unroll
  for (int t = 0; t < NI; ++t) {
    int cb = (wave * NI + t) * 64;
    int c = cb + lane;
    int row = c / CPR;
    int colb = c % CPR;
    if (SWZ) colb ^= (row & 3);
    __builtin_amdgcn_global_load_lds(
        (const __attribute__((address_space(1))) unsigned int*)(g + row * ld + colb * 8),
        (__attribute__((address_space(3))) unsigned int*)(lds + cb * 8),
        16, 0, 0);
  }
}

// ---------------- prep kernels ----------------

// uvqk (512 x 2048 fp32) -> uvqkT (2048 x 512 bf16)  [B^T layout for GEMM]
__global__ void k_tr_uvqk(const float* __restrict__ uvqk, __bf16* __restrict__ uvqkT) {
  __shared__ float tile[32][33];
  int n0 = blockIdx.x * 32, k0 = blockIdx.y * 32;
  int tx = threadIdx.x, ty = threadIdx.y;
  for (int i = ty; i < 32; i += 8)
    tile[i][tx] = uvqk[(k0 + i) * 2048 + n0 + tx];
  __syncthreads();
  for (int i = ty; i < 32; i += 8)
    uvqkT[(n0 + i) * 512 + k0 + tx] = (__bf16)tile[tx][i];
}

// fused: blocks <8192 do layer_norm(x)->bf16 (one block per row);
// blocks >=8192 convert o_weight fp32->bf16.
__global__ void k_prep(const float* __restrict__ x, __bf16* __restrict__ nx,
                       const float* __restrict__ ow, __bf16* __restrict__ owb) {
  int bid = blockIdx.x, t = threadIdx.x;
  if (bid >= 8192) {
    int i = (bid - 8192) * 128 + t;
    float4 v = ((const float4*)ow)[i];
    ushort4 o4;
    o4.x = f2bf(v.x); o4.y = f2bf(v.y); o4.z = f2bf(v.z); o4.w = f2bf(v.w);
    ((ushort4*)owb)[i] = o4;
    return;
  }
  float4 v = ((const float4*)(x + (size_t)bid * 512))[t];
  float s = v.x + v.y + v.z + v.w;
  float ss = v.x * v.x + v.y * v.y + v.z * v.z + v.w * v.w;
#pragma unroll
  for (int o = 32; o > 0; o >>= 1) { s += __shfl_down(s, o); ss += __shfl_down(ss, o); }
  __shared__ float red[4];
  if ((t & 63) == 0) { red[(t >> 6) * 2] = s; red[(t >> 6) * 2 + 1] = ss; }
  __syncthreads();
  s = red[0] + red[2]; ss = red[1] + red[3];
  float mu = s * (1.0f / 512.0f);
  float var = ss * (1.0f / 512.0f) - mu * mu;
  float rs = rsqrtf(var + 1e-6f);
  ushort4 o4;
  o4.x = f2bf((v.x - mu) * rs); o4.y = f2bf((v.y - mu) * rs);
  o4.z = f2bf((v.z - mu) * rs); o4.w = f2bf((v.w - mu) * rs);
  ((ushort4*)(nx + (size_t)bid * 512))[t] = o4;
}

// ---------------- projection GEMM: mm = silu(nx @ uvqk) ----------------
// M=8192, N=2048, K=512. 128x128 tile, 4 waves 2x2, 16x16x32 MFMA.
// v segment: scaled by 1/2048 (folds the attention /n into V) and stored
// transposed as vt[b, c(h*64+dl), n].
__global__ __launch_bounds__(256, 2) void k_proj(
    const __bf16* __restrict__ A, const __bf16* __restrict__ Bt,
    __bf16* __restrict__ u, __bf16* __restrict__ qn,
    __bf16* __restrict__ kn, __bf16* __restrict__ vt) {
  __shared__ __bf16 As[128 * 32], Bs[128 * 32];
  int tid = threadIdx.x, wave = tid >> 6, lane = tid & 63;
  int lr = lane & 15, lq = lane >> 4;
  int bn = blockIdx.x, bm = blockIdx.y;
  const __bf16* Ag = A + (size_t)bm * 128 * 512;
  const __bf16* Bg = Bt + (size_t)bn * 128 * 512;
  int wm = (wave >> 1) * 64, wn = (wave & 1) * 64;
  f32x4 acc[4][4] = {};
  for (int k0 = 0; k0 < 512; k0 += 32) {
    stage16<4, 2>(Ag + k0, 512, As, wave, lane);
    stage16<4, 2>(Bg + k0, 512, Bs, wave, lane);
    __syncthreads();
    bf16x8 a[4], bb[4];
#pragma unroll
    for (int i = 0; i < 4; ++i)
      a[i] = *(const bf16x8*)(As + (wm + i * 16 + lr) * 32 + lq * 8);
#pragma unroll
    for (int j = 0; j < 4; ++j)
      bb[j] = *(const bf16x8*)(Bs + (wn + j * 16 + lr) * 32 + lq * 8);
#pragma unroll
    for (int i = 0; i < 4; ++i)
#pragma unroll
      for (int j = 0; j < 4; ++j)
        acc[i][j] = __builtin_amdgcn_mfma_f32_16x16x32_bf16(a[i], bb[j], acc[i][j], 0, 0, 0);
    __syncthreads();
  }
  int seg = bn >> 2;
  int cb = (bn & 3) * 128 + wn;
  int rb0 = bm * 128 + wm + lq * 4;
  if (seg == 1) {
    const float sc = 1.0f / 2048.0f;
#pragma unroll
    for (int i = 0; i < 4; ++i) {
      int rb = rb0 + i * 16;
      int b = rb >> 11, n = rb & 2047;
#pragma unroll
      for (int j = 0; j < 4; ++j) {
        int c = cb + j * 16 + lr;  // h*64+dl
        ushort4 w;
        w.x = f2bf(silu_f(acc[i][j][0]) * sc);
        w.y = f2bf(silu_f(acc[i][j][1]) * sc);
        w.z = f2bf(silu_f(acc[i][j][2]) * sc);
        w.w = f2bf(silu_f(acc[i][j][3]) * sc);
        *(ushort4*)(vt + ((size_t)(b * 512 + c)) * 2048 + n) = w;
      }
    }
  } else {
    __bf16* dst = (seg == 0) ? u : ((seg == 2) ? qn : kn);
#pragma unroll
    for (int i = 0; i < 4; ++i) {
      int rb = rb0 + i * 16;
#pragma unroll
      for (int j = 0; j < 4; ++j) {
        int c = cb + j * 16 + lr;
#pragma unroll
        for (int rg = 0; rg < 4; ++rg)
          dst[(size_t)(rb + rg) * 512 + c] = (__bf16)silu_f(acc[i][j][rg]);
      }
    }
  }
}

// ---------------- fused causal silu-attention (v2.1) ----------------
// 32x32x16 MFMA, swizzled LDS panels, dbuf K/V prefetch (1 barrier/m-tile),
// in-register P transform via shfl_xor(32), cross-wave pair reduction.
__global__ __launch_bounds__(256, 2) void k_attn(
    const __bf16* __restrict__ qn, const __bf16* __restrict__ kn,
    const __bf16* __restrict__ vt, __bf16* __restrict__ attn) {
  __shared__ __bf16 lds[40960];  // 80 KB
  __bf16* Qs = lds;              // [2 panels][128 n][32 k]
  __bf16* Ks0 = lds + 8192;      // [2 panels][128 m][32 k]
  __bf16* Ks1 = lds + 16384;
  __bf16* Vs0 = lds + 24576;     // [4 panels][64 dl][32 m]
  __bf16* Vs1 = lds + 32768;

  int bh = blockIdx.x;
  int yy = blockIdx.y;
  int qt = (yy < 8) ? yy : 23 - yy;  // heavy/light pairing
  int b = bh >> 3, h = bh & 7;
  int tid = threadIdx.x, wave = tid >> 6, lane = tid & 63;
  int l31 = lane & 31, lh = lane >> 5;
  int n0 = qt * 128;
  const __bf16* Qg = qn + (size_t)(b * 2048 + n0) * 512 + h * 64;
  const __bf16* Kg = kn + (size_t)(b * 2048) * 512 + h * 64;
  const __bf16* Vg = vt + (size_t)(b * 512 + h * 64) * 2048;

  stage16<4, 2, true>(Qg, 512, Qs, wave, lane);
  stage16<4, 2, true>(Qg + 32, 512, Qs + 4096, wave, lane);
  stage16<4, 2, true>(Kg, 512, Ks0, wave, lane);
  stage16<4, 2, true>(Kg + 32, 512, Ks0 + 4096, wave, lane);
#pragma unroll
  for (int p = 0; p < 4; ++p)
    stage16<4, 1, true>(Vg + p * 32, 2048, Vs0 + p * 2048, wave, lane);
  __syncthreads();

  int wm = (wave >> 1) * 64, wn = (wave & 1) * 64;

  // Q B-frags cached: qf[j][ks]: Q[n=wn+j*32+l31][k=ks*16+lh*8 ..+8]
  bf16x8 qf[2][4];
#pragma unroll
  for (int j = 0; j < 2; ++j)
#pragma unroll
    for (int ks = 0; ks < 4; ++ks) {
      int row = wn + j * 32 + l31;
      int kidx = ks * 16 + lh * 8;
      qf[j][ks] = *(const bf16x8*)(Qs + (kidx >> 5) * 4096 + row * 32 +
                                   (((kidx & 31)) ^ ((row & 3) * 8)));
    }

  f32x16 po[2][2] = {};  // [idl][j]

  for (int mt = 0; mt <= qt; ++mt) {
    const __bf16* Kc = (mt & 1) ? Ks1 : Ks0;
    const __bf16* Vc = (mt & 1) ? Vs1 : Vs0;
    if (mt < qt) {
      __bf16* Kn_ = (mt & 1) ? Ks0 : Ks1;
      __bf16* Vn_ = (mt & 1) ? Vs0 : Vs1;
      const __bf16* Kgm = Kg + (size_t)(mt + 1) * 128 * 512;
      stage16<4, 2, true>(Kgm, 512, Kn_, wave, lane);
      stage16<4, 2, true>(Kgm + 32, 512, Kn_ + 4096, wave, lane);
#pragma unroll
      for (int p = 0; p < 4; ++p)
        stage16<4, 1, true>(Vg + (mt + 1) * 128 + p * 32, 2048, Vn_ + p * 2048, wave, lane);
    }
    // S^T[m][n] = K . Q^T : tiles i(m) x j(n), K-dim 64 = 4 ksteps
    f32x16 s[2][2] = {};
#pragma unroll
    for (int ks = 0; ks < 4; ++ks) {
      int kidx = ks * 16 + lh * 8;
      bf16x8 ak[2];
#pragma unroll
      for (int i = 0; i < 2; ++i) {
        int row = wm + i * 32 + l31;
        ak[i] = *(const bf16x8*)(Kc + (kidx >> 5) * 4096 + row * 32 +
                                 ((kidx & 31) ^ ((row & 3) * 8)));
      }
#pragma unroll
      for (int i = 0; i < 2; ++i)
#pragma unroll
        for (int j = 0; j < 2; ++j)
          s[i][j] = __builtin_amdgcn_mfma_f32_32x32x16_bf16(ak[i], qf[j][ks], s[i][j], 0, 0, 0);
    }
    // silu + causal mask + pack + cross-half exchange -> PV B-frags
    bool diag = (mt == qt);
    bool lo = (lh == 0);
    bf16x8 pf[2][4];  // [j][kstep over wave's 64 m]
#pragma unroll
    for (int i = 0; i < 2; ++i) {
      int mbase = wm + i * 32;
#pragma unroll
      for (int j = 0; j < 2; ++j) {
        int nbase = wn + j * 32;
        bool full = diag && (mbase > nbase + 31);
        unsigned pk[8];
        if (full) {
#pragma unroll
          for (int q = 0; q < 8; ++q) pk[q] = 0u;
        } else {
          bool dtile = diag && (mbase + 31 > nbase);
          int mb = mbase + 4 * lh;
          int ncol = nbase + l31;
          float vv[16];
#pragma unroll
          for (int r = 0; r < 16; ++r) {
            float xx = s[i][j][r];
            float p = xx * __builtin_amdgcn_rcpf(1.0f + __expf(-xx));
            if (dtile) {
              int row = mb + (r & 3) + 8 * (r >> 2);
              if (row > ncol) p = 0.0f;
            }
            vv[r] = p;
          }
#pragma unroll
          for (int q = 0; q < 8; ++q) pk[q] = pk2(vv[2 * q], vv[2 * q + 1]);
        }
        unsigned xa = __shfl_xor(lo ? pk[2] : pk[0], 32);
        unsigned xb = __shfl_xor(lo ? pk[3] : pk[1], 32);
        unsigned xc = __shfl_xor(lo ? pk[6] : pk[4], 32);
        unsigned xd = __shfl_xor(lo ? pk[7] : pk[5], 32);
        union { bf16x8 v; unsigned u[4]; } f0, f1;
        f0.u[0] = lo ? pk[0] : xa;  f0.u[1] = lo ? pk[1] : xb;
        f0.u[2] = lo ? xa : pk[2];  f0.u[3] = lo ? xb : pk[3];
        f1.u[0] = lo ? pk[4] : xc;  f1.u[1] = lo ? pk[5] : xd;
        f1.u[2] = lo ? xc : pk[6];  f1.u[3] = lo ? xd : pk[7];
        pf[j][i * 2 + 0] = f0.v;
        pf[j][i * 2 + 1] = f1.v;
      }
    }
    // out^T[dl][n] += V^T . P^T  (K-dim = wave's 64 m)
#pragma unroll
    for (int t4 = 0; t4 < 4; ++t4) {
      int kidx = wm + t4 * 16 + lh * 8;
      bf16x8 av[2];
#pragma unroll
      for (int idl = 0; idl < 2; ++idl) {
        int row = idl * 32 + l31;
        av[idl] = *(const bf16x8*)(Vc + (kidx >> 5) * 2048 + row * 32 +
                                   ((kidx & 31) ^ ((row & 3) * 8)));
      }
#pragma unroll
      for (int idl = 0; idl < 2; ++idl)
#pragma unroll
        for (int j = 0; j < 2; ++j)
          po[idl][j] = __builtin_amdgcn_mfma_f32_32x32x16_bf16(av[idl], pf[j][t4], po[idl][j], 0, 0, 0);
    }
    __syncthreads();
  }

  // cross-wave pair reduction: waves 2,3 (m 64..127) -> waves 0,1
  float* red = (float*)lds;  // 8192 f32 (Qs+Ks0 region)
  if (wave >= 2) {
    float* dst = red + (wave - 2) * 4096;
#pragma unroll
    for (int idl = 0; idl < 2; ++idl)
#pragma unroll
      for (int j = 0; j < 2; ++j)
#pragma unroll
        for (int r = 0; r < 16; ++r)
          dst[((idl * 2 + j) * 16 + r) * 64 + lane] = po[idl][j][r];
  }
  __syncthreads();
  __bf16* bo = lds + 24576;  // bounce [128 n][72] bf16
  if (wave < 2) {
    float* src = red + wave * 4096;
#pragma unroll
    for (int idl = 0; idl < 2; ++idl)
#pragma unroll
      for (int j = 0; j < 2; ++j) {
#pragma unroll
        for (int r = 0; r < 16; ++r)
          po[idl][j][r] += src[((idl * 2 + j) * 16 + r) * 64 + lane];
        int nrow = wn + j * 32 + l31;
#pragma unroll
        for (int g = 0; g < 4; ++g) {
          int dl0 = idl * 32 + g * 8 + lh * 4;
          ushort4 w;
          w.x = f2bf(po[idl][j][4 * g + 0]); w.y = f2bf(po[idl][j][4 * g + 1]);
          w.z = f2bf(po[idl][j][4 * g + 2]); w.w = f2bf(po[idl][j][4 * g + 3]);
          *(ushort4*)(bo + nrow * 72 + dl0) = w;
        }
      }
  }
  __syncthreads();
  // coalesced store: attn[b, n, h*64 + dl]; each thread 32 bf16 = 4 x 16B
  {
    int n = tid >> 1, part = tid & 1;
    __bf16* gdst = attn + (size_t)(b * 2048 + n0 + n) * 512 + h * 64 + part * 32;
    const __bf16* lsrc = bo + n * 72 + part * 32;
#pragma unroll
    for (int c = 0; c < 4; ++c)
      *(uint4*)(gdst + c * 8) = *(const uint4*)(lsrc + c * 8);
  }
}

// o_input = u * layer_norm(attn), one block (128 thr) per row
__global__ void k_oinput(const __bf16* __restrict__ attn, const __bf16* __restrict__ u,
                         __bf16* __restrict__ oin) {
  int r = blockIdx.x, t = threadIdx.x;
  ushort4 a4 = ((const ushort4*)(attn + (size_t)r * 512))[t];
  float a0 = bfu2f(a4.x), a1 = bfu2f(a4.y), a2 = bfu2f(a4.z), a3 = bfu2f(a4.w);
  float s = a0 + a1 + a2 + a3;
  float ss = a0 * a0 + a1 * a1 + a2 * a2 + a3 * a3;
#pragma unroll
  for (int o = 32; o > 0; o >>= 1) { s += __shfl_down(s, o); ss += __shfl_down(ss, o); }
  __shared__ float red[4];
  if ((t & 63) == 0) { red[(t >> 6) * 2] = s; red[(t >> 6) * 2 + 1] = ss; }
  __syncthreads();
  s = red[0] + red[2]; ss = red[1] + red[3];
  float mu = s * (1.0f / 512.0f);
  float var = ss * (1.0f / 512.0f) - mu * mu;
  float rs = rsqrtf(var + 1e-6f);
  ushort4 u4 = ((const ushort4*)(u + (size_t)r * 512))[t];
  ushort4 o4;
  o4.x = f2bf(bfu2f(u4.x) * (a0 - mu) * rs);
  o4.y = f2bf(bfu2f(u4.y) * (a1 - mu) * rs);
  o4.z = f2bf(bfu2f(u4.z) * (a2 - mu) * rs);
  o4.w = f2bf(bfu2f(u4.w) * (a3 - mu) * rs);
  ((ushort4*)(oin + (size_t)r * 512))[t] = o4;
}

// out = o_in @ ow^T + bias + x.  M=8192, N=512, K=512
__global__ __launch_bounds__(256, 2) void k_out(
    const __bf16* __restrict__ A, const __bf16* __restrict__ Bt,
    const float* __restrict__ bias, const float* __restrict__ x,
    float* __restrict__ out) {
  __shared__ __bf16 As[128 * 32], Bs[128 * 32];
  int tid = threadIdx.x, wave = tid >> 6, lane = tid & 63;
  int lr = lane & 15, lq = lane >> 4;
  int bn = blockIdx.x, bm = blockIdx.y;
  const __bf16* Ag = A + (size_t)bm * 128 * 512;
  const __bf16* Bg = Bt + (size_t)bn * 128 * 512;
  int wm = (wave >> 1) * 64, wn = (wave & 1) * 64;
  f32x4 acc[4][4] = {};
  for (int k0 = 0; k0 < 512; k0 += 32) {
    stage16<4, 2>(Ag + k0, 512, As, wave, lane);
    stage16<4, 2>(Bg + k0, 512, Bs, wave, lane);
    __syncthreads();
    bf16x8 a[4], bb[4];
#pragma unroll
    for (int i = 0; i < 4; ++i)
      a[i] = *(const bf16x8*)(As + (wm + i * 16 + lr) * 32 + lq * 8);
#pragma unroll
    for (int j = 0; j < 4; ++j)
      bb[j] = *(const bf16x8*)(Bs + (wn + j * 16 + lr) * 32 + lq * 8);
#pragma unroll
    for (int i = 0; i < 4; ++i)
#pragma unroll
      for (int j = 0; j < 4; ++j)
        acc[i][j] = __builtin_amdgcn_mfma_f32_16x16x32_bf16(a[i], bb[j], acc[i][j], 0, 0, 0);
    __syncthreads();
  }
  int cb = bn * 128 + wn;
  int rb0 = bm * 128 + wm + lq * 4;
#pragma unroll
  for (int j = 0; j < 4; ++j) {
    int c = cb + j * 16 + lr;
    float bv = bias[c];
#pragma unroll
    for (int i = 0; i < 4; ++i) {
      int rb = rb0 + i * 16;
#pragma unroll
      for (int rg = 0; rg < 4; ++rg) {
        size_t idx = (size_t)(rb + rg) * 512 + c;
        out[idx] = acc[i][j][rg] + bv + x[idx];
      }
    }
  }
}

extern "C" void kernel_launch(void* const* d_in, const int* in_sizes, int n_in,
                              void* d_out, int out_size, void* d_ws, size_t ws_size,
                              hipStream_t stream) {
  const float* x = (const float*)d_in[0];
  // d_in[1] = attention_mask (deterministic causal tril) -- applied analytically
  const float* uvqk = (const float*)d_in[2];
  const float* ow = (const float*)d_in[3];
  const float* ob = (const float*)d_in[4];
  float* out = (float*)d_out;

  char* w = (char*)d_ws;
  const size_t MB8 = 8u * 1024 * 1024;
  __bf16* nx    = (__bf16*)(w);             // 8 MB
  __bf16* u     = (__bf16*)(w + MB8);       // 8 MB
  __bf16* qn    = (__bf16*)(w + 2 * MB8);   // 8 MB
  __bf16* kn    = (__bf16*)(w + 3 * MB8);   // 8 MB
  __bf16* vt    = (__bf16*)(w + 4 * MB8);   // 8 MB (b, c, n) pre-scaled 1/2048
  __bf16* uvqkT = (__bf16*)(w + 5 * MB8);   // 2 MB
  __bf16* owb   = (__bf16*)(w + 5 * MB8 + 2097152);  // 0.5 MB
  __bf16* attn  = nx;  // nx dead after k_proj
  __bf16* o_in  = qn;  // qn dead after k_attn

  k_tr_uvqk<<<dim3(64, 16), dim3(32, 8), 0, stream>>>(uvqk, uvqkT);
  k_prep<<<8704, 128, 0, stream>>>(x, nx, ow, owb);
  k_proj<<<dim3(16, 64), 256, 0, stream>>>(nx, uvqkT, u, qn, kn, vt);
  k_attn<<<dim3(32, 16), 256, 0, stream>>>(qn, kn, vt, attn);
  k_oinput<<<8192, 128, 0, stream>>>(attn, u, o_in);
  k_out<<<dim3(4, 64), 256, 0, stream>>>(o_in, owb, ob, x, out);
}

// Round 4
// 202.907 us; speedup vs baseline: 1.1926x; 1.1001x over previous
//
#include <hip/hip_runtime.h>

typedef __bf16 bf16x8 __attribute__((ext_vector_type(8)));
typedef float f32x4 __attribute__((ext_vector_type(4)));
typedef float f32x16 __attribute__((ext_vector_type(16)));

__device__ __forceinline__ unsigned short f2bf(float f) {
  return __builtin_bit_cast(unsigned short, (__bf16)f);
}
__device__ __forceinline__ float bfu2f(unsigned short b) {
  unsigned int u = ((unsigned int)b) << 16;
  return __builtin_bit_cast(float, u);
}
// fast silu: x * rcp(1+exp(-x)).
__device__ __forceinline__ float silu_f(float x) {
  return x * __builtin_amdgcn_rcpf(1.0f + __expf(-x));
}
__device__ __forceinline__ unsigned pk2(float a, float b) {
  return (unsigned)f2bf(a) | ((unsigned)f2bf(b) << 16);
}

// Stage a tile into LDS via global_load_lds (16B/lane). Logical layout:
// [rows][CPR*8 cols] bf16, row pitch CPR*16 bytes. Stored chunk slot s of row r
// holds SOURCE column block s^(r&SWZ). Readers fetch block b at slot b^(r&SWZ).
// With CPR=8 (128B rows, SWZ=7) or CPR=16 (256B rows, SWZ=15) every 8-lane
// b128 read group hits 8 distinct 16B chunks -> conflict-free.
template<int CPR, int NI, int SWZ>
__device__ __forceinline__ void stage16(const __bf16* __restrict__ g, int ld,
                                        __bf16* lds, int wave, int lane) {
#pragma unroll
  for (int t = 0; t < NI; ++t) {
    int cb = (wave * NI + t) * 64;
    int c = cb + lane;
    int row = c / CPR;
    int colb = (c % CPR) ^ (row & SWZ);
    __builtin_amdgcn_global_load_lds(
        (const __attribute__((address_space(1))) unsigned int*)(g + row * ld + colb * 8),
        (__attribute__((address_space(3))) unsigned int*)(lds + cb * 8),
        16, 0, 0);
  }
}

// ---------------- prep kernels ----------------

// uvqk (512 x 2048 fp32) -> uvqkT (2048 x 512 bf16)
__global__ void k_tr_uvqk(const float* __restrict__ uvqk, __bf16* __restrict__ uvqkT) {
  __shared__ float tile[32][33];
  int n0 = blockIdx.x * 32, k0 = blockIdx.y * 32;
  int tx = threadIdx.x, ty = threadIdx.y;
  for (int i = ty; i < 32; i += 8)
    tile[i][tx] = uvqk[(k0 + i) * 2048 + n0 + tx];
  __syncthreads();
  for (int i = ty; i < 32; i += 8)
    uvqkT[(n0 + i) * 512 + k0 + tx] = (__bf16)tile[tx][i];
}

// fused: blocks <8192 layer_norm(x)->bf16; blocks >=8192 o_weight fp32->bf16.
__global__ void k_prep(const float* __restrict__ x, __bf16* __restrict__ nx,
                       const float* __restrict__ ow, __bf16* __restrict__ owb) {
  int bid = blockIdx.x, t = threadIdx.x;
  if (bid >= 8192) {
    int i = (bid - 8192) * 128 + t;
    float4 v = ((const float4*)ow)[i];
    ushort4 o4;
    o4.x = f2bf(v.x); o4.y = f2bf(v.y); o4.z = f2bf(v.z); o4.w = f2bf(v.w);
    ((ushort4*)owb)[i] = o4;
    return;
  }
  float4 v = ((const float4*)(x + (size_t)bid * 512))[t];
  float s = v.x + v.y + v.z + v.w;
  float ss = v.x * v.x + v.y * v.y + v.z * v.z + v.w * v.w;
#pragma unroll
  for (int o = 32; o > 0; o >>= 1) { s += __shfl_down(s, o); ss += __shfl_down(ss, o); }
  __shared__ float red[4];
  if ((t & 63) == 0) { red[(t >> 6) * 2] = s; red[(t >> 6) * 2 + 1] = ss; }
  __syncthreads();
  s = red[0] + red[2]; ss = red[1] + red[3];
  float mu = s * (1.0f / 512.0f);
  float var = ss * (1.0f / 512.0f) - mu * mu;
  float rs = rsqrtf(var + 1e-6f);
  ushort4 o4;
  o4.x = f2bf((v.x - mu) * rs); o4.y = f2bf((v.y - mu) * rs);
  o4.z = f2bf((v.z - mu) * rs); o4.w = f2bf((v.w - mu) * rs);
  ((ushort4*)(nx + (size_t)bid * 512))[t] = o4;
}

// ---------------- projection GEMM: mm = silu(nx @ uvqk) ----------------
// 128x128 tile, 4 waves 2x2, 16x16x32 MFMA, 64-wide swizzled panels.
__global__ __launch_bounds__(256, 3) void k_proj(
    const __bf16* __restrict__ A, const __bf16* __restrict__ Bt,
    __bf16* __restrict__ u, __bf16* __restrict__ qn,
    __bf16* __restrict__ kn, __bf16* __restrict__ vt) {
  __shared__ __bf16 As[128 * 64], Bs[128 * 64];
  int tid = threadIdx.x, wave = tid >> 6, lane = tid & 63;
  int lr = lane & 15, lq = lane >> 4;
  int bn = blockIdx.x, bm = blockIdx.y;
  const __bf16* Ag = A + (size_t)bm * 128 * 512;
  const __bf16* Bg = Bt + (size_t)bn * 128 * 512;
  int wm = (wave >> 1) * 64, wn = (wave & 1) * 64;
  f32x4 acc[4][4] = {};
  for (int k0 = 0; k0 < 512; k0 += 64) {
    stage16<8, 4, 7>(Ag + k0, 512, As, wave, lane);
    stage16<8, 4, 7>(Bg + k0, 512, Bs, wave, lane);
    __syncthreads();
#pragma unroll
    for (int kk = 0; kk < 2; ++kk) {
      int b = kk * 4 + lq;
      bf16x8 a[4], bb[4];
#pragma unroll
      for (int i = 0; i < 4; ++i) {
        int row = wm + i * 16 + lr;
        a[i] = *(const bf16x8*)(As + row * 64 + ((b ^ (row & 7)) * 8));
      }
#pragma unroll
      for (int j = 0; j < 4; ++j) {
        int row = wn + j * 16 + lr;
        bb[j] = *(const bf16x8*)(Bs + row * 64 + ((b ^ (row & 7)) * 8));
      }
#pragma unroll
      for (int i = 0; i < 4; ++i)
#pragma unroll
        for (int j = 0; j < 4; ++j)
          acc[i][j] = __builtin_amdgcn_mfma_f32_16x16x32_bf16(a[i], bb[j], acc[i][j], 0, 0, 0);
    }
    __syncthreads();
  }
  int seg = bn >> 2;
  int cb = (bn & 3) * 128 + wn;
  int rb0 = bm * 128 + wm + lq * 4;
  if (seg == 1) {
#pragma unroll
    for (int i = 0; i < 4; ++i) {
      int rb = rb0 + i * 16;
      int b = rb >> 11, n = rb & 2047;
#pragma unroll
      for (int j = 0; j < 4; ++j) {
        int c = cb + j * 16 + lr;  // h*64+dl
        ushort4 w;
        w.x = f2bf(silu_f(acc[i][j][0]) * (1.0f / 2048.0f));
        w.y = f2bf(silu_f(acc[i][j][1]) * (1.0f / 2048.0f));
        w.z = f2bf(silu_f(acc[i][j][2]) * (1.0f / 2048.0f));
        w.w = f2bf(silu_f(acc[i][j][3]) * (1.0f / 2048.0f));
        *(ushort4*)(vt + ((size_t)(b * 512 + c)) * 2048 + n) = w;
      }
    }
  } else {
    __bf16* dst = (seg == 0) ? u : ((seg == 2) ? qn : kn);
#pragma unroll
    for (int i = 0; i < 4; ++i) {
      int rb = rb0 + i * 16;
#pragma unroll
      for (int j = 0; j < 4; ++j) {
        int c = cb + j * 16 + lr;
#pragma unroll
        for (int rg = 0; rg < 4; ++rg)
          dst[(size_t)(rb + rg) * 512 + c] = (__bf16)silu_f(acc[i][j][rg]);
      }
    }
  }
}

// ---------------- fused causal silu-attention (v3) ----------------
// Block = (bh, p, half): processes rows [half*64,+64) of q-tile p, then of
// q-tile 15-p -> exactly 17 half-tiles per block (perfect balance).
// 32x32x16 MFMA; conflict-free swizzled panels; dbuf K/V; in-register P
// transform via shfl_xor(32); cross-wave pair reduction per phase.
__global__ __launch_bounds__(256, 2) void k_attn(
    const __bf16* __restrict__ qn, const __bf16* __restrict__ kn,
    const __bf16* __restrict__ vt, __bf16* __restrict__ attn) {
  __shared__ __bf16 lds[36864];  // 72 KB
  __bf16* Qs  = lds;             // [64 n][64 k]   8 KB
  __bf16* Ks0 = lds + 4096;      // [128 m][64 k] 16 KB
  __bf16* Ks1 = lds + 12288;
  __bf16* Vs0 = lds + 20480;     // [64 dl][128 m] 16 KB
  __bf16* Vs1 = lds + 28672;

  int bh = blockIdx.x;
  int p = blockIdx.y;        // 0..7
  int half = blockIdx.z;     // 0..1
  int b = bh >> 3, hd = bh & 7;
  int tid = threadIdx.x, wave = tid >> 6, lane = tid & 63;
  int l31 = lane & 31, lh = lane >> 5;
  int wm = (wave >> 1) * 64, wn = (wave & 1) * 32;
  const __bf16* Kg = kn + (size_t)(b * 2048) * 512 + hd * 64;
  const __bf16* Vg = vt + (size_t)(b * 512 + hd * 64) * 2048;

  for (int ph = 0; ph < 2; ++ph) {
    int qtx = ph ? (15 - p) : p;
    int n0 = qtx * 128;
    const __bf16* Qg = qn + (size_t)(b * 2048 + n0 + half * 64) * 512 + hd * 64;
    if (ph) __syncthreads();  // epilogue-A LDS reads done before restaging
    stage16<8, 2, 7>(Qg, 512, Qs, wave, lane);
    stage16<8, 4, 7>(Kg, 512, Ks0, wave, lane);
    stage16<16, 4, 15>(Vg, 2048, Vs0, wave, lane);
    __syncthreads();

    // Q B-frags cached in registers for the whole phase
    bf16x8 qf[4];
#pragma unroll
    for (int ks = 0; ks < 4; ++ks) {
      int bk = (ks * 16 + lh * 8) >> 3;
      int row = wn + l31;
      qf[ks] = *(const bf16x8*)(Qs + row * 64 + ((bk ^ (row & 7)) * 8));
    }

    f32x16 po[2] = {};  // out^T acc: [idl] over dl 2x32, n = wn+l31

    for (int mt = 0; mt <= qtx; ++mt) {
      const __bf16* Kc = (mt & 1) ? Ks1 : Ks0;
      const __bf16* Vc = (mt & 1) ? Vs1 : Vs0;
      if (mt < qtx) {
        __bf16* Kn_ = (mt & 1) ? Ks0 : Ks1;
        __bf16* Vn_ = (mt & 1) ? Vs0 : Vs1;
        stage16<8, 4, 7>(Kg + (size_t)(mt + 1) * 128 * 512, 512, Kn_, wave, lane);
        stage16<16, 4, 15>(Vg + (mt + 1) * 128, 2048, Vn_, wave, lane);
      }
      // S^T[m 64][n 32] = K . Q^T
      f32x16 s[2] = {};
#pragma unroll
      for (int ks = 0; ks < 4; ++ks) {
        int bk = (ks * 16 + lh * 8) >> 3;
        bf16x8 ak[2];
#pragma unroll
        for (int i = 0; i < 2; ++i) {
          int row = wm + i * 32 + l31;
          ak[i] = *(const bf16x8*)(Kc + row * 64 + ((bk ^ (row & 7)) * 8));
        }
#pragma unroll
        for (int i = 0; i < 2; ++i)
          s[i] = __builtin_amdgcn_mfma_f32_32x32x16_bf16(ak[i], qf[ks], s[i], 0, 0, 0);
      }
      // silu + causal mask + pack + cross-half exchange -> PV B-frags
      bool diag = (mt == qtx);
      bool lo = (lh == 0);
      int nb = half * 64 + wn;  // col base within the 128-wide S tile
      bf16x8 pf[4];
#pragma unroll
      for (int i = 0; i < 2; ++i) {
        int mbase = wm + i * 32;
        bool full = diag && (mbase > nb + 31);
        unsigned pk[8];
        if (full) {
#pragma unroll
          for (int q = 0; q < 8; ++q) pk[q] = 0u;
        } else {
          bool dtile = diag && (mbase + 31 > nb);
          int mb = mbase + 4 * lh;
          int ncol = nb + l31;
          float vv[16];
#pragma unroll
          for (int r = 0; r < 16; ++r) {
            float xx = s[i][r];
            float pv = xx * __builtin_amdgcn_rcpf(1.0f + __expf(-xx));
            if (dtile) {
              int row = mb + (r & 3) + 8 * (r >> 2);
              if (row > ncol) pv = 0.0f;
            }
            vv[r] = pv;
          }
#pragma unroll
          for (int q = 0; q < 8; ++q) pk[q] = pk2(vv[2 * q], vv[2 * q + 1]);
        }
        unsigned xa = __shfl_xor(lo ? pk[2] : pk[0], 32);
        unsigned xb = __shfl_xor(lo ? pk[3] : pk[1], 32);
        unsigned xc = __shfl_xor(lo ? pk[6] : pk[4], 32);
        unsigned xd = __shfl_xor(lo ? pk[7] : pk[5], 32);
        union { bf16x8 v; unsigned u[4]; } f0, f1;
        f0.u[0] = lo ? pk[0] : xa;  f0.u[1] = lo ? pk[1] : xb;
        f0.u[2] = lo ? xa : pk[2];  f0.u[3] = lo ? xb : pk[3];
        f1.u[0] = lo ? pk[4] : xc;  f1.u[1] = lo ? pk[5] : xd;
        f1.u[2] = lo ? xc : pk[6];  f1.u[3] = lo ? xd : pk[7];
        pf[i * 2 + 0] = f0.v;
        pf[i * 2 + 1] = f1.v;
      }
      // out^T[dl][n] += V^T . P^T  (K-dim = wave's 64 m)
#pragma unroll
      for (int t4 = 0; t4 < 4; ++t4) {
        int bk = (wm + t4 * 16 + lh * 8) >> 3;
        bf16x8 av[2];
#pragma unroll
        for (int idl = 0; idl < 2; ++idl) {
          int row = idl * 32 + l31;
          av[idl] = *(const bf16x8*)(Vc + row * 128 + ((bk ^ (row & 15)) * 8));
        }
#pragma unroll
        for (int idl = 0; idl < 2; ++idl)
          po[idl] = __builtin_amdgcn_mfma_f32_32x32x16_bf16(av[idl], pf[t4], po[idl], 0, 0, 0);
      }
      __syncthreads();
    }

    // cross-wave pair reduction: waves 2,3 (m 64..127) -> waves 0,1
    float* red = (float*)lds;        // 4096 f32 = 16 KB
    __bf16* bo = lds + 8192;         // [64 n][72] bf16 bounce
    if (wave >= 2) {
      float* dst = red + (wave - 2) * 2048;
#pragma unroll
      for (int idl = 0; idl < 2; ++idl)
#pragma unroll
        for (int r = 0; r < 16; ++r)
          dst[(idl * 16 + r) * 64 + lane] = po[idl][r];
    }
    __syncthreads();
    if (wave < 2) {
      float* src = red + wave * 2048;
#pragma unroll
      for (int idl = 0; idl < 2; ++idl) {
#pragma unroll
        for (int r = 0; r < 16; ++r)
          po[idl][r] += src[(idl * 16 + r) * 64 + lane];
        int nrow = wn + l31;
#pragma unroll
        for (int g = 0; g < 4; ++g) {
          int dl0 = idl * 32 + g * 8 + lh * 4;
          ushort4 w;
          w.x = f2bf(po[idl][4 * g + 0]); w.y = f2bf(po[idl][4 * g + 1]);
          w.z = f2bf(po[idl][4 * g + 2]); w.w = f2bf(po[idl][4 * g + 3]);
          *(ushort4*)(bo + nrow * 72 + dl0) = w;
        }
      }
    }
    __syncthreads();
    // coalesced store: attn[b, n0+half*64+n, hd*64 + dl], 32B/thread
    {
      int n = tid >> 2, c0 = (tid & 3) * 16;
      __bf16* gdst = attn + (size_t)(b * 2048 + n0 + half * 64 + n) * 512 + hd * 64 + c0;
      const __bf16* lsrc = bo + n * 72 + c0;
      *(uint4*)(gdst) = *(const uint4*)(lsrc);
      *(uint4*)(gdst + 8) = *(const uint4*)(lsrc + 8);
    }
  }
}

// o_input = u * layer_norm(attn), one block (128 thr) per row
__global__ void k_oinput(const __bf16* __restrict__ attn, const __bf16* __restrict__ u,
                         __bf16* __restrict__ oin) {
  int r = blockIdx.x, t = threadIdx.x;
  ushort4 a4 = ((const ushort4*)(attn + (size_t)r * 512))[t];
  float a0 = bfu2f(a4.x), a1 = bfu2f(a4.y), a2 = bfu2f(a4.z), a3 = bfu2f(a4.w);
  float s = a0 + a1 + a2 + a3;
  float ss = a0 * a0 + a1 * a1 + a2 * a2 + a3 * a3;
#pragma unroll
  for (int o = 32; o > 0; o >>= 1) { s += __shfl_down(s, o); ss += __shfl_down(ss, o); }
  __shared__ float red[4];
  if ((t & 63) == 0) { red[(t >> 6) * 2] = s; red[(t >> 6) * 2 + 1] = ss; }
  __syncthreads();
  s = red[0] + red[2]; ss = red[1] + red[3];
  float mu = s * (1.0f / 512.0f);
  float var = ss * (1.0f / 512.0f) - mu * mu;
  float rs = rsqrtf(var + 1e-6f);
  ushort4 u4 = ((const ushort4*)(u + (size_t)r * 512))[t];
  ushort4 o4;
  o4.x = f2bf(bfu2f(u4.x) * (a0 - mu) * rs);
  o4.y = f2bf(bfu2f(u4.y) * (a1 - mu) * rs);
  o4.z = f2bf(bfu2f(u4.z) * (a2 - mu) * rs);
  o4.w = f2bf(bfu2f(u4.w) * (a3 - mu) * rs);
  ((ushort4*)(oin + (size_t)r * 512))[t] = o4;
}

// out = o_in @ ow^T + bias + x.  M=8192, N=512, K=512
__global__ __launch_bounds__(256, 3) void k_out(
    const __bf16* __restrict__ A, const __bf16* __restrict__ Bt,
    const float* __restrict__ bias, const float* __restrict__ x,
    float* __restrict__ out) {
  __shared__ __bf16 As[128 * 64], Bs[128 * 64];
  int tid = threadIdx.x, wave = tid >> 6, lane = tid & 63;
  int lr = lane & 15, lq = lane >> 4;
  int bn = blockIdx.x, bm = blockIdx.y;
  const __bf16* Ag = A + (size_t)bm * 128 * 512;
  const __bf16* Bg = Bt + (size_t)bn * 128 * 512;
  int wm = (wave >> 1) * 64, wn = (wave & 1) * 64;
  f32x4 acc[4][4] = {};
  for (int k0 = 0; k0 < 512; k0 += 64) {
    stage16<8, 4, 7>(Ag + k0, 512, As, wave, lane);
    stage16<8, 4, 7>(Bg + k0, 512, Bs, wave, lane);
    __syncthreads();
#pragma unroll
    for (int kk = 0; kk < 2; ++kk) {
      int b = kk * 4 + lq;
      bf16x8 a[4], bb[4];
#pragma unroll
      for (int i = 0; i < 4; ++i) {
        int row = wm + i * 16 + lr;
        a[i] = *(const bf16x8*)(As + row * 64 + ((b ^ (row & 7)) * 8));
      }
#pragma unroll
      for (int j = 0; j < 4; ++j) {
        int row = wn + j * 16 + lr;
        bb[j] = *(const bf16x8*)(Bs + row * 64 + ((b ^ (row & 7)) * 8));
      }
#pragma unroll
      for (int i = 0; i < 4; ++i)
#pragma unroll
        for (int j = 0; j < 4; ++j)
          acc[i][j] = __builtin_amdgcn_mfma_f32_16x16x32_bf16(a[i], bb[j], acc[i][j], 0, 0, 0);
    }
    __syncthreads();
  }
  int cb = bn * 128 + wn;
  int rb0 = bm * 128 + wm + lq * 4;
#pragma unroll
  for (int j = 0; j < 4; ++j) {
    int c = cb + j * 16 + lr;
    float bv = bias[c];
#pragma unroll
    for (int i = 0; i < 4; ++i) {
      int rb = rb0 + i * 16;
#pragma unroll
      for (int rg = 0; rg < 4; ++rg) {
        size_t idx = (size_t)(rb + rg) * 512 + c;
        out[idx] = acc[i][j][rg] + bv + x[idx];
      }
    }
  }
}

extern "C" void kernel_launch(void* const* d_in, const int* in_sizes, int n_in,
                              void* d_out, int out_size, void* d_ws, size_t ws_size,
                              hipStream_t stream) {
  const float* x = (const float*)d_in[0];
  // d_in[1] = attention_mask (deterministic causal tril) -- applied analytically
  const float* uvqk = (const float*)d_in[2];
  const float* ow = (const float*)d_in[3];
  const float* ob = (const float*)d_in[4];
  float* out = (float*)d_out;

  char* w = (char*)d_ws;
  const size_t MB8 = 8u * 1024 * 1024;
  __bf16* nx    = (__bf16*)(w);             // 8 MB
  __bf16* u     = (__bf16*)(w + MB8);       // 8 MB
  __bf16* qn    = (__bf16*)(w + 2 * MB8);   // 8 MB
  __bf16* kn    = (__bf16*)(w + 3 * MB8);   // 8 MB
  __bf16* vt    = (__bf16*)(w + 4 * MB8);   // 8 MB (b, c, n) pre-scaled 1/2048
  __bf16* uvqkT = (__bf16*)(w + 5 * MB8);   // 2 MB
  __bf16* owb   = (__bf16*)(w + 5 * MB8 + 2097152);  // 0.5 MB
  __bf16* attn  = nx;  // nx dead after k_proj
  __bf16* o_in  = qn;  // qn dead after k_attn

  k_tr_uvqk<<<dim3(64, 16), dim3(32, 8), 0, stream>>>(uvqk, uvqkT);
  k_prep<<<8704, 128, 0, stream>>>(x, nx, ow, owb);
  k_proj<<<dim3(16, 64), 256, 0, stream>>>(nx, uvqkT, u, qn, kn, vt);
  k_attn<<<dim3(32, 8, 2), 256, 0, stream>>>(qn, kn, vt, attn);
  k_oinput<<<8192, 128, 0, stream>>>(attn, u, o_in);
  k_out<<<dim3(4, 64), 256, 0, stream>>>(o_in, owb, ob, x, out);
}